// Round 5
// baseline (2380.005 us; speedup 1.0000x reference)
//
#include <hip/hip_runtime.h>
#include <hip/hip_bf16.h>
#include <math.h>

// PPOActorRNN on MI355X — round 9: hierarchical (per-XCD) grid barrier.
// R8 evidence: time invariant under -45% FETCH and under half occupancy;
// time scales with nblk at fixed round count. Model: per-round cost =
// nblk serialized device-scope ACQ_REL RMWs (~250cy each) at one address
// (512x250x25 = 1.33ms == measured GRU time). Fix: two-level barrier —
// 8 per-XCD arrival counters in parallel (64 serialized RMWs each), then
// 8 XCD reps on the global counter; two-level generation wake. All
// primitives identical in kind to the R5-proven pattern.
// Also: 3-deep W prefetch (s+2 lookahead) to cover post-invalidate LLC
// latency in tail-round jobs. Job map + keys unchanged from R8 (passed).

#define TTT 256
#define BBB 256
#define DDD 512
#define ACT 32
#define MMM (TTT*BBB)

typedef short bf16x8 __attribute__((ext_vector_type(8)));
typedef float f32x4 __attribute__((ext_vector_type(4)));
typedef unsigned short u16;

__device__ inline u16 f2bf(float f) {
    unsigned int u = __float_as_uint(f);
    u += 0x7fffu + ((u >> 16) & 1u);
    return (u16)(u >> 16);
}
__device__ inline float bf2f(u16 h) { return __uint_as_float(((unsigned int)h) << 16); }

// ---------------- transpose + cvt: out[n*ostride + k] = bf16(in[k*512 + n]) ----
__global__ __launch_bounds__(256) void transpose_cvt_k(
    const float* __restrict__ in, u16* __restrict__ out, int ostride)
{
    __shared__ float tile[32][33];
    const int c = threadIdx.x & 31;
    const int r0 = threadIdx.x >> 5;
    const int bx = blockIdx.x, by = blockIdx.y;
#pragma unroll
    for (int p = 0; p < 4; p++) {
        int r = r0 + p * 8;
        tile[r][c] = in[(size_t)(by * 32 + r) * DDD + bx * 32 + c];
    }
    __syncthreads();
#pragma unroll
    for (int p = 0; p < 4; p++) {
        int r = r0 + p * 8;
        out[(size_t)(bx * 32 + r) * ostride + by * 32 + c] = f2bf(tile[c][r]);
    }
}

// ---------------- MFMA GEMM (parallel phases), unchanged ----------------
template<bool AF32>
__global__ __launch_bounds__(256) void gemm_bf16_k(
    const void* __restrict__ Aptr, const u16* __restrict__ Bt,
    const float* __restrict__ bias, u16* __restrict__ C, int N)
{
    __shared__ u16 As[128 * 64];
    __shared__ u16 Bs[128 * 64];
    const int tid = threadIdx.x;
    const int row0 = blockIdx.x * 128;
    const int col0 = blockIdx.y * 128;
    const int lane = tid & 63, wid = tid >> 6;
    const int wr = wid >> 1, wc = wid & 1;
    const int lm = lane & 15, lq = lane >> 4;

    f32x4 acc[4][4];
#pragma unroll
    for (int i = 0; i < 4; i++)
#pragma unroll
        for (int j = 0; j < 4; j++) acc[i][j] = (f32x4){0.f, 0.f, 0.f, 0.f};

    for (int kc = 0; kc < 8; kc++) {
        const int k0 = kc * 64;
#pragma unroll
        for (int p = 0; p < 4; p++) {
            int g = p * 256 + tid;
            int row = g >> 3, j = g & 7;
            bf16x8 v;
            if (AF32) {
                const float* s = (const float*)Aptr + (size_t)(row0 + row) * DDD + k0 + j * 8;
                float4 a0 = *(const float4*)s;
                float4 a1 = *(const float4*)(s + 4);
                v[0] = (short)f2bf(a0.x); v[1] = (short)f2bf(a0.y);
                v[2] = (short)f2bf(a0.z); v[3] = (short)f2bf(a0.w);
                v[4] = (short)f2bf(a1.x); v[5] = (short)f2bf(a1.y);
                v[6] = (short)f2bf(a1.z); v[7] = (short)f2bf(a1.w);
            } else {
                v = *(const bf16x8*)((const u16*)Aptr + (size_t)(row0 + row) * DDD + k0 + j * 8);
            }
            *(bf16x8*)(As + row * 64 + ((j ^ (row & 7)) << 3)) = v;
        }
#pragma unroll
        for (int p = 0; p < 4; p++) {
            int g = p * 256 + tid;
            int n = g >> 3, j = g & 7;
            bf16x8 v = *(const bf16x8*)(Bt + (size_t)(col0 + n) * DDD + k0 + j * 8);
            *(bf16x8*)(Bs + n * 64 + ((j ^ (n & 7)) << 3)) = v;
        }
        __syncthreads();
#pragma unroll
        for (int ks = 0; ks < 2; ks++) {
            bf16x8 af[4], bfr[4];
#pragma unroll
            for (int i = 0; i < 4; i++) {
                int row = wr * 64 + i * 16 + lm;
                af[i] = *(const bf16x8*)(As + row * 64 + (((ks * 4 + lq) ^ (row & 7)) << 3));
            }
#pragma unroll
            for (int j = 0; j < 4; j++) {
                int n = wc * 64 + j * 16 + lm;
                bfr[j] = *(const bf16x8*)(Bs + n * 64 + (((ks * 4 + lq) ^ (n & 7)) << 3));
            }
#pragma unroll
            for (int i = 0; i < 4; i++)
#pragma unroll
                for (int j = 0; j < 4; j++)
                    acc[i][j] = __builtin_amdgcn_mfma_f32_16x16x32_bf16(af[i], bfr[j], acc[i][j], 0, 0, 0);
        }
        __syncthreads();
    }
#pragma unroll
    for (int j = 0; j < 4; j++) {
        int col = col0 + wc * 64 + j * 16 + lm;
        float bj = bias[col];
#pragma unroll
        for (int i = 0; i < 4; i++) {
            int rb = row0 + wr * 64 + i * 16 + lq * 4;
#pragma unroll
            for (int r = 0; r < 4; r++)
                C[(size_t)(rb + r) * N + col] = f2bf(acc[i][j][r] + bj);
        }
    }
}

// ---------------- LayerNorm + ReLU in-place on bf16 [M x 512] ----------------
__global__ __launch_bounds__(256) void ln_relu_k(
    u16* __restrict__ X, const float* __restrict__ gamma, const float* __restrict__ beta)
{
    const int tid = threadIdx.x;
    const int lane = tid & 63;
    const size_t row = (size_t)blockIdx.x * 4 + (tid >> 6);
    const int c0 = lane * 8;
    u16* px = X + row * DDD + c0;
    bf16x8 v = *(const bf16x8*)px;
    float f[8]; float s = 0.f, s2 = 0.f;
#pragma unroll
    for (int i = 0; i < 8; i++) { f[i] = bf2f((u16)v[i]); s += f[i]; s2 += f[i] * f[i]; }
#pragma unroll
    for (int off = 32; off; off >>= 1) { s += __shfl_xor(s, off); s2 += __shfl_xor(s2, off); }
    float mu = s * (1.f / (float)DDD);
    float rs = rsqrtf(s2 * (1.f / (float)DDD) - mu * mu + 1e-6f);
    float4 g0 = *(const float4*)(gamma + c0), g1 = *(const float4*)(gamma + c0 + 4);
    float4 b0 = *(const float4*)(beta + c0),  b1 = *(const float4*)(beta + c0 + 4);
    float gg[8] = {g0.x, g0.y, g0.z, g0.w, g1.x, g1.y, g1.z, g1.w};
    float bb[8] = {b0.x, b0.y, b0.z, b0.w, b1.x, b1.y, b1.z, b1.w};
    bf16x8 o;
#pragma unroll
    for (int i = 0; i < 8; i++) {
        float yv = (f[i] - mu) * rs * gg[i] + bb[i];
        o[i] = (short)f2bf(fmaxf(yv, 0.f));
    }
    *(bf16x8*)px = o;
}

// ---------------- logits ----------------
__global__ __launch_bounds__(256) void logits_k(
    const u16* __restrict__ AM, const float* __restrict__ Wa,
    const float* __restrict__ ba, const int* __restrict__ avail,
    float* __restrict__ out)
{
    __shared__ float xs[8][DDD];
    const int tid = threadIdx.x;
    const size_t row0 = (size_t)blockIdx.x * 8;
    for (int g = tid; g < 8 * 64; g += 256) {
        int r = g >> 6, c8 = (g & 63) * 8;
        bf16x8 v = *(const bf16x8*)(AM + (row0 + r) * DDD + c8);
#pragma unroll
        for (int i = 0; i < 8; i++) xs[r][c8 + i] = bf2f((u16)v[i]);
    }
    __syncthreads();
    const int r = tid >> 5, a = tid & 31;
    float acc = 0.f;
    for (int k = 0; k < DDD; k += 4) {
        float4 xv = *(const float4*)&xs[r][k];
        acc = fmaf(xv.x, Wa[(k + 0) * ACT + a], acc);
        acc = fmaf(xv.y, Wa[(k + 1) * ACT + a], acc);
        acc = fmaf(xv.z, Wa[(k + 2) * ACT + a], acc);
        acc = fmaf(xv.w, Wa[(k + 3) * ACT + a], acc);
    }
    size_t o = (row0 + r) * ACT + a;
    float v = acc + ba[a];
    if (avail[o] == 0) v -= 1e10f;
    out[o] = v;
}

// ---------------- list building ----------------
// key: 0 = done rows (h==0, skipH), 1 = t0 rows (h from `hidden`),
//      d+1 = depth-d rows otherwise. Parent key strictly < child key.
__global__ __launch_bounds__(256) void depth_build_k(
    const int* __restrict__ dones,
    int* __restrict__ keyA, int* __restrict__ pidxA,
    int* __restrict__ counts, int* __restrict__ maxk)
{
    __shared__ int lc[512];
    __shared__ int lmax;
    const int b = threadIdx.x;
    lc[b] = 0; lc[b + 256] = 0;
    if (b == 0) lmax = 0;
    __syncthreads();
    int dprev = 0, mx = 0;
    for (int t = 0; t < TTT; t++) {
        int pos = t * BBB + b;
        int d, pi, k;
        if (dones[pos] != 0)       { d = 0; pi = -1;       k = 0; }
        else if (t == 0)           { d = 0; pi = -2 - b;   k = 1; }
        else                       { d = dprev + 1; pi = pos - BBB; k = d + 1; }
        keyA[pos] = k; pidxA[pos] = pi;
        atomicAdd(&lc[k], 1);
        mx = max(mx, k);
        dprev = d;
    }
    atomicMax(&lmax, mx);
    __syncthreads();
    counts[b] = lc[b];
    counts[b + 256] = lc[b + 256];
    if (b == 0) *maxk = lmax;
}

__global__ void scan_k(const int* __restrict__ counts, int* __restrict__ offs)
{
    if (threadIdx.x == 0) {
        int s = 0;
        for (int i = 0; i < 512; i++) { offs[i] = s; s += counts[i]; }
    }
}

__global__ __launch_bounds__(256) void scatter_k(
    const int* __restrict__ keyA, const int* __restrict__ offs,
    int* __restrict__ cursor, int* __restrict__ list)
{
    __shared__ int lcnt[512];
    __shared__ int lbase[512];
    const int tid = threadIdx.x;
    lcnt[tid] = 0; lcnt[tid + 256] = 0;
    __syncthreads();
    int pos = blockIdx.x * 256 + tid;
    int k = keyA[pos];
    int rank = atomicAdd(&lcnt[k], 1);
    __syncthreads();
    for (int q = tid; q < 512; q += 256) {
        int c = lcnt[q];
        lbase[q] = c ? atomicAdd(&cursor[q], c) : 0;
    }
    __syncthreads();
    list[offs[k] + lbase[k] + rank] = pos;
}

// ---------------- hierarchical grid barrier ----------------
// Level 1: per-XCD arrival counter (8 addresses -> 8-way parallel RMW chains).
// Level 2: 8 XCD reps on global counter. Two-level generation wake.
// Primitive kinds identical to the R5-proven barrier (relaxed spin on
// RELEASE-stored gen; ACQ_REL fetch_add; relaxed counter reset).
__device__ inline void tree_barrier(int* xcdCnt, int* xcdGen, int* gCnt, int* gGen,
                                    int e, int nxb)
{
    __syncthreads();
    if (threadIdx.x == 0) {
        __threadfence();   // publish this block's Y writes device-wide
        int* xc = xcdCnt + e * 32;
        int* xg = xcdGen + e * 32;
        int gx = __hip_atomic_load(xg, __ATOMIC_RELAXED, __HIP_MEMORY_SCOPE_AGENT);
        int a = __hip_atomic_fetch_add(xc, 1, __ATOMIC_ACQ_REL, __HIP_MEMORY_SCOPE_AGENT);
        if (a == nxb - 1) {
            // last block of this XCD -> XCD rep
            __hip_atomic_store(xc, 0, __ATOMIC_RELAXED, __HIP_MEMORY_SCOPE_AGENT);
            int gg = __hip_atomic_load(gGen, __ATOMIC_RELAXED, __HIP_MEMORY_SCOPE_AGENT);
            int b = __hip_atomic_fetch_add(gCnt, 1, __ATOMIC_ACQ_REL, __HIP_MEMORY_SCOPE_AGENT);
            if (b == 7) {
                __hip_atomic_store(gCnt, 0, __ATOMIC_RELAXED, __HIP_MEMORY_SCOPE_AGENT);
                __hip_atomic_store(gGen, gg + 1, __ATOMIC_RELEASE, __HIP_MEMORY_SCOPE_AGENT);
            } else {
                while (__hip_atomic_load(gGen, __ATOMIC_RELAXED, __HIP_MEMORY_SCOPE_AGENT) == gg)
                    __builtin_amdgcn_s_sleep(2);
                (void)__hip_atomic_load(gGen, __ATOMIC_ACQUIRE, __HIP_MEMORY_SCOPE_AGENT);
            }
            __hip_atomic_store(xg, gx + 1, __ATOMIC_RELEASE, __HIP_MEMORY_SCOPE_AGENT);
        } else {
            while (__hip_atomic_load(xg, __ATOMIC_RELAXED, __HIP_MEMORY_SCOPE_AGENT) == gx)
                __builtin_amdgcn_s_sleep(2);
            (void)__hip_atomic_load(xg, __ATOMIC_ACQUIRE, __HIP_MEMORY_SCOPE_AGENT);
        }
        __threadfence();
    }
    __syncthreads();
}

// ---------------- round-based GRU, XCD-grouped jobs, tree barrier ----------------
template<bool YF32>
__global__ __launch_bounds__(256, 2) void gru_depth_k(
    const u16* __restrict__ E, const float* __restrict__ hidden,
    const u16* __restrict__ Wstk, const float* __restrict__ bi,
    const float* __restrict__ bhn,
    const int* __restrict__ list, const int* __restrict__ offs,
    const int* __restrict__ counts, const int* __restrict__ maxk,
    const int* __restrict__ pidxA,
    void* __restrict__ Yv, float* __restrict__ hid_out,
    int* __restrict__ xcdCnt, int* __restrict__ xcdGen,
    int* __restrict__ gCnt, int* __restrict__ gGen)
{
    __shared__ u16 As[64 * 256];         // 32 KB, one 256-K chunk of 64 rows
    __shared__ int posL[64], pidxL[64];
    __shared__ int sAnyH;
    const int tid = threadIdx.x;
    const int w = tid >> 6, lane = tid & 63;
    const int lm = lane & 15, lq = lane >> 4;
    const int nblk = gridDim.x;
    const int e   = blockIdx.x & 7;      // XCD id
    const int xb  = blockIdx.x >> 3;     // block index within XCD
    const int nxb = nblk >> 3;           // blocks per XCD

    const int MK = *maxk;
    for (int k = 0; k <= MK; k++) {
        const int nd = counts[k];
        const int off = offs[k];
        const int ntiles = (nd + 63) >> 6;
        const int ntl = (ntiles - e + 7) >> 3;   // tiles with rt%8==e
        const int njl = (ntl > 0) ? (ntl << 2) : 0;
        for (int lj = xb; lj < njl; lj += nxb) {
            const int rt = ((lj >> 2) << 3) + e;
            const int panel = lj & 3;
            bool hasH = false;
            if (tid < 64) {
                int idx = rt * 64 + tid;
                int p = (idx < nd) ? list[off + idx] : -1;
                int pi = (p >= 0) ? pidxA[p] : -1;
                posL[tid] = p;
                pidxL[tid] = pi;
                hasH = (p >= 0) && (pi != -1);
                unsigned long long m = __ballot(hasH);
                if (tid == 0) sAnyH = (m != 0ULL);
            }
            __syncthreads();
            const bool skipH = !sAnyH;

            f32x4 a01[4][4], aX[4][2], aH[4][2];
#pragma unroll
            for (int mt = 0; mt < 4; mt++) {
#pragma unroll
                for (int q = 0; q < 4; q++) a01[mt][q] = (f32x4){0.f, 0.f, 0.f, 0.f};
#pragma unroll
                for (int q = 0; q < 2; q++) {
                    aX[mt][q] = (f32x4){0.f, 0.f, 0.f, 0.f};
                    aH[mt][q] = (f32x4){0.f, 0.f, 0.f, 0.f};
                }
            }

            const int cb = panel * 128 + w * 32;
            const u16* wp[6];
#pragma unroll
            for (int ct = 0; ct < 6; ct++) {
                int gate = ct >> 1;
                int nglob = gate * 512 + cb + ((ct & 1) << 4) + lm;
                wp[ct] = Wstk + (size_t)nglob * 1024 + lq * 8;
            }

            const int nkc = skipH ? 2 : 4;
            for (int kc = 0; kc < nkc; kc++) {
                // stage A chunk: 64 rows x 256 K (gathered rows)
#pragma unroll
                for (int it = 0; it < 8; it++) {
                    int g = it * 256 + tid;
                    int row = g >> 5, jg = g & 31;
                    int kglob = kc * 256 + jg * 8;
                    bf16x8 v = (bf16x8){0, 0, 0, 0, 0, 0, 0, 0};
                    int p = posL[row];
                    if (p >= 0) {
                        if (kglob < 512) {
                            v = *(const bf16x8*)(E + (size_t)p * DDD + kglob);
                        } else {
                            int k2 = kglob - 512;
                            int pi = pidxL[row];
                            if (pi >= 0) {
                                if (YF32) {
                                    const float* s = (const float*)Yv + (size_t)pi * DDD + k2;
                                    float4 a0 = *(const float4*)s;
                                    float4 a1 = *(const float4*)(s + 4);
                                    v[0] = (short)f2bf(a0.x); v[1] = (short)f2bf(a0.y);
                                    v[2] = (short)f2bf(a0.z); v[3] = (short)f2bf(a0.w);
                                    v[4] = (short)f2bf(a1.x); v[5] = (short)f2bf(a1.y);
                                    v[6] = (short)f2bf(a1.z); v[7] = (short)f2bf(a1.w);
                                } else {
                                    v = *(const bf16x8*)((const u16*)Yv + (size_t)pi * DDD + k2);
                                }
                            } else if (pi <= -2) {
                                const float* s = hidden + (size_t)(-pi - 2) * DDD + k2;
                                float4 a0 = *(const float4*)s;
                                float4 a1 = *(const float4*)(s + 4);
                                v[0] = (short)f2bf(a0.x); v[1] = (short)f2bf(a0.y);
                                v[2] = (short)f2bf(a0.z); v[3] = (short)f2bf(a0.w);
                                v[4] = (short)f2bf(a1.x); v[5] = (short)f2bf(a1.y);
                                v[6] = (short)f2bf(a1.z); v[7] = (short)f2bf(a1.w);
                            }
                        }
                    }
                    *(bf16x8*)(As + row * 256 + ((jg ^ (row & 31)) << 3)) = v;
                }
                __syncthreads();

                const bool xpart = (kc < 2);
                const int kgb = kc * 256;
                bf16x8 bfA[6], bfB[6], bfC[6];

#define LOADW(B, KG) \
    _Pragma("unroll") \
    for (int ct = 0; ct < 6; ct++) B[ct] = *(const bf16x8*)(wp[ct] + (KG));

#define COMPW(B, S) \
    _Pragma("unroll") \
    for (int mt = 0; mt < 4; mt++) { \
        int row = mt * 16 + lm; \
        int jgr = (S) * 4 + lq; \
        bf16x8 af = *(const bf16x8*)(As + row * 256 + ((jgr ^ (row & 31)) << 3)); \
        a01[mt][0] = __builtin_amdgcn_mfma_f32_16x16x32_bf16(af, B[0], a01[mt][0], 0, 0, 0); \
        a01[mt][1] = __builtin_amdgcn_mfma_f32_16x16x32_bf16(af, B[1], a01[mt][1], 0, 0, 0); \
        a01[mt][2] = __builtin_amdgcn_mfma_f32_16x16x32_bf16(af, B[2], a01[mt][2], 0, 0, 0); \
        a01[mt][3] = __builtin_amdgcn_mfma_f32_16x16x32_bf16(af, B[3], a01[mt][3], 0, 0, 0); \
        if (xpart) { \
            aX[mt][0] = __builtin_amdgcn_mfma_f32_16x16x32_bf16(af, B[4], aX[mt][0], 0, 0, 0); \
            aX[mt][1] = __builtin_amdgcn_mfma_f32_16x16x32_bf16(af, B[5], aX[mt][1], 0, 0, 0); \
        } else { \
            aH[mt][0] = __builtin_amdgcn_mfma_f32_16x16x32_bf16(af, B[4], aH[mt][0], 0, 0, 0); \
            aH[mt][1] = __builtin_amdgcn_mfma_f32_16x16x32_bf16(af, B[5], aH[mt][1], 0, 0, 0); \
        } \
    }

                // 3-deep software pipeline: W load s+2 in flight over COMPW(s..s+1)
                LOADW(bfA, kgb + 0 * 32);
                LOADW(bfB, kgb + 1 * 32);
                LOADW(bfC, kgb + 2 * 32);
                COMPW(bfA, 0); LOADW(bfA, kgb + 3 * 32);
                COMPW(bfB, 1); LOADW(bfB, kgb + 4 * 32);
                COMPW(bfC, 2); LOADW(bfC, kgb + 5 * 32);
                COMPW(bfA, 3); LOADW(bfA, kgb + 6 * 32);
                COMPW(bfB, 4); LOADW(bfB, kgb + 7 * 32);
                COMPW(bfC, 5);
                COMPW(bfA, 6);
                COMPW(bfB, 7);
#undef LOADW
#undef COMPW
                __syncthreads();
            }

            // wave-local gate combine + Y write
#pragma unroll
            for (int mt = 0; mt < 4; mt++) {
#pragma unroll
                for (int r = 0; r < 4; r++) {
                    int row = mt * 16 + lq * 4 + r;
                    int p = posL[row];
                    if (p < 0) continue;
                    int pi = pidxL[row];
#pragma unroll
                    for (int ct = 0; ct < 2; ct++) {
                        int cglob = cb + ct * 16 + lm;
                        float rpre = a01[mt][ct][r]     + bi[cglob];
                        float zpre = a01[mt][2 + ct][r] + bi[512 + cglob];
                        float xn   = aX[mt][ct][r]      + bi[1024 + cglob];
                        float hn   = aH[mt][ct][r]      + bhn[cglob];
                        float rg = 1.f / (1.f + __expf(-rpre));
                        float zg = 1.f / (1.f + __expf(-zpre));
                        float targ = xn + rg * hn;
                        float t2 = __expf(-2.f * fabsf(targ));
                        float ng = copysignf((1.f - t2) / (1.f + t2), targ);
                        float hp = 0.f;
                        if (pi >= 0)
                            hp = YF32 ? ((const float*)Yv)[(size_t)pi * DDD + cglob]
                                      : bf2f(((const u16*)Yv)[(size_t)pi * DDD + cglob]);
                        else if (pi <= -2)
                            hp = hidden[(size_t)(-pi - 2) * DDD + cglob];
                        float hnew = (1.f - zg) * ng + zg * hp;
                        if (YF32) ((float*)Yv)[(size_t)p * DDD + cglob] = hnew;
                        else      ((u16*)Yv)[(size_t)p * DDD + cglob] = f2bf(hnew);
                    }
                }
            }
            __syncthreads();   // protect posL/As for next job
        }
        tree_barrier(xcdCnt, xcdGen, gCnt, gGen, e, nxb);
    }

    // final hidden: out[b*512+c] = Y[(255*256+b)*512+c]
    for (int i = blockIdx.x * 256 + tid; i < BBB * DDD; i += nblk * 256) {
        int b = i >> 9, c = i & 511;
        size_t yi = (size_t)(65280 + b) * DDD + c;
        hid_out[i] = YF32 ? ((const float*)Yv)[yi] : bf2f(((const u16*)Yv)[yi]);
    }
}

extern "C" void kernel_launch(void* const* d_in, const int* in_sizes, int n_in,
                              void* d_out, int out_size, void* d_ws, size_t ws_size,
                              hipStream_t stream)
{
    const float* hidden = (const float*)d_in[0];
    const float* obs    = (const float*)d_in[1];
    const int*   dones  = (const int*)d_in[2];
    const int*   avail  = (const int*)d_in[3];
    const float* Wm     = (const float*)d_in[4];
    const float* bm     = (const float*)d_in[5];
    const float* lns    = (const float*)d_in[6];
    const float* lnb    = (const float*)d_in[7];
    const float* Wi     = (const float*)d_in[8];
    const float* bi     = (const float*)d_in[9];
    const float* Wh     = (const float*)d_in[10];
    const float* bhn    = (const float*)d_in[11];
    const float* Wo     = (const float*)d_in[12];
    const float* bo     = (const float*)d_in[13];
    const float* ln2s   = (const float*)d_in[14];
    const float* ln2b   = (const float*)d_in[15];
    const float* Wa     = (const float*)d_in[16];
    const float* ba     = (const float*)d_in[17];
    float* out = (float*)d_out;

    // workspace layout
    char* w = (char*)d_ws;
    u16* Wstk = (u16*)w;  w += (size_t)1536 * 1024 * 2;      // 3 MB
    u16* WmT  = (u16*)w;  w += (size_t)3 * DDD * DDD * 2;
    u16* WoT  = (u16*)w;  w += (size_t)DDD * DDD * 2;
    int* meta = (int*)w;  w += 16384;
    int* counts = meta;              // 512
    int* offs   = meta + 512;        // 512
    int* cursor = meta + 1024;       // 512
    int* maxk   = meta + 1536;
    int* xcdCnt = meta + 1600;       // 8 x stride-32
    int* xcdGen = meta + 1856;       // 8 x stride-32
    int* gCnt   = meta + 2112;
    int* gGen   = meta + 2144;
    int* keyA   = (int*)w;  w += (size_t)MMM * 4;
    int* pidxA  = (int*)w;  w += (size_t)MMM * 4;
    int* list   = (int*)w;  w += (size_t)MMM * 4;
    u16* P = (u16*)w;       w += (size_t)MMM * DDD * 2;      // 64 MB
    void* Yv = (void*)w;
    const size_t base = (size_t)(w - (char*)d_ws);
    const bool yf32 = (ws_size >= base + (size_t)MMM * DDD * 4);

    // prep: weight transposes + meta zero
    dim3 tgrid(16, 16);
    for (int l = 0; l < 3; l++)
        transpose_cvt_k<<<tgrid, 256, 0, stream>>>(Wm + (size_t)l * DDD * DDD, WmT + (size_t)l * DDD * DDD, DDD);
    transpose_cvt_k<<<tgrid, 256, 0, stream>>>(Wo, WoT, DDD);
    for (int g = 0; g < 3; g++) {
        transpose_cvt_k<<<tgrid, 256, 0, stream>>>(Wi + (size_t)g * DDD * DDD, Wstk + (size_t)g * 512 * 1024, 1024);
        transpose_cvt_k<<<tgrid, 256, 0, stream>>>(Wh + (size_t)g * DDD * DDD, Wstk + (size_t)g * 512 * 1024 + 512, 1024);
    }
    hipMemsetAsync(meta, 0, 16384, stream);

    // key lists (done-first within depth 0)
    depth_build_k<<<1, 256, 0, stream>>>(dones, keyA, pidxA, counts, maxk);
    scan_k<<<1, 64, 0, stream>>>(counts, offs);
    scatter_k<<<MMM / 256, 256, 0, stream>>>(keyA, offs, cursor, list);

    // encoder: obs -> P -> Y -> P
    u16* Yq = (u16*)Yv;
    gemm_bf16_k<true><<<dim3(MMM / 128, 4), 256, 0, stream>>>(obs, WmT, bm, P, DDD);
    ln_relu_k<<<dim3(MMM / 4), 256, 0, stream>>>(P, lns, lnb);
    gemm_bf16_k<false><<<dim3(MMM / 128, 4), 256, 0, stream>>>(P, WmT + (size_t)DDD * DDD, bm + DDD, Yq, DDD);
    ln_relu_k<<<dim3(MMM / 4), 256, 0, stream>>>(Yq, lns + DDD, lnb + DDD);
    gemm_bf16_k<false><<<dim3(MMM / 128, 4), 256, 0, stream>>>(Yq, WmT + (size_t)2 * DDD * DDD, bm + 2 * DDD, P, DDD);
    ln_relu_k<<<dim3(MMM / 4), 256, 0, stream>>>(P, lns + 2 * DDD, lnb + 2 * DDD);

    // persistent-block GRU; grid sized to guaranteed co-residency
    {
        const void* fptr = yf32 ? (const void*)gru_depth_k<true>
                                : (const void*)gru_depth_k<false>;
        int occ = 0;
        hipError_t e = hipOccupancyMaxActiveBlocksPerMultiprocessor(&occ, fptr, 256, 0);
        if (e != hipSuccess || occ < 1) occ = 2;
        if (occ > 4) occ = 4;
        dim3 grid(occ * 256);
        if (yf32)
            gru_depth_k<true><<<grid, 256, 0, stream>>>(
                P, hidden, Wstk, bi, bhn, list, offs, counts, maxk, pidxA,
                Yv, out, xcdCnt, xcdGen, gCnt, gGen);
        else
            gru_depth_k<false><<<grid, 256, 0, stream>>>(
                P, hidden, Wstk, bi, bhn, list, offs, counts, maxk, pidxA,
                Yv, out, xcdCnt, xcdGen, gCnt, gGen);
    }

    // head: Y -> P, LN, logits
    if (yf32)
        gemm_bf16_k<true><<<dim3(MMM / 128, 4), 256, 0, stream>>>(Yv, WoT, bo, P, DDD);
    else
        gemm_bf16_k<false><<<dim3(MMM / 128, 4), 256, 0, stream>>>(Yv, WoT, bo, P, DDD);
    ln_relu_k<<<dim3(MMM / 4), 256, 0, stream>>>(P, ln2s, ln2b);
    logits_k<<<dim3(MMM / 8), 256, 0, stream>>>(P, Wa, ba, avail, out + BBB * DDD);
}

// Round 6
// 2006.478 us; speedup vs baseline: 1.1862x; 1.1862x over previous
//
#include <hip/hip_runtime.h>
#include <hip/hip_bf16.h>
#include <math.h>

// PPOActorRNN on MI355X — round 10: rep-only-fence barrier + 4-block tail.
// Evidence chain: R9 falsified RMW-serialization (8x fewer RMWs/chain, worse).
// Surviving model: per-round cost = per-leader __threadfence (buffer_wbl2,
// an XCD-L2 writeback drain), 64-128 serialized per XCD per round:
//   R4 (1024 leaders) ~137us/round; R5/R8 (512) ~49us/round; R9 kept fences
//   -> no change. Fix:
//  - fat_barrier: RELAXED per-XCD arrival; ONLY the last arriver per XCD
//    fences (8 wbl2/round total, not 1024); leaders wake with one ACQUIRE
//    (invalidate, parallel). Same primitive kinds as the R5-proven barrier.
//  - tail depths (counts<=64, ~15 of ~26 rounds): handled entirely by 4
//    blocks on XCD 0 with a 4-participant R5-verbatim barrier; all other
//    blocks exit. Removes ~15 full-grid barriers.
// Job body, XCD-grouped mapping, done-first keys, 2-deep W pipeline: R8
// verbatim (passed).

#define TTT 256
#define BBB 256
#define DDD 512
#define ACT 32
#define MMM (TTT*BBB)

typedef short bf16x8 __attribute__((ext_vector_type(8)));
typedef float f32x4 __attribute__((ext_vector_type(4)));
typedef unsigned short u16;

__device__ inline u16 f2bf(float f) {
    unsigned int u = __float_as_uint(f);
    u += 0x7fffu + ((u >> 16) & 1u);
    return (u16)(u >> 16);
}
__device__ inline float bf2f(u16 h) { return __uint_as_float(((unsigned int)h) << 16); }

#define AL_RLX(p)  __hip_atomic_load((p), __ATOMIC_RELAXED, __HIP_MEMORY_SCOPE_AGENT)
#define AL_ACQ(p)  __hip_atomic_load((p), __ATOMIC_ACQUIRE, __HIP_MEMORY_SCOPE_AGENT)

// ---------------- transpose + cvt: out[n*ostride + k] = bf16(in[k*512 + n]) ----
__global__ __launch_bounds__(256) void transpose_cvt_k(
    const float* __restrict__ in, u16* __restrict__ out, int ostride)
{
    __shared__ float tile[32][33];
    const int c = threadIdx.x & 31;
    const int r0 = threadIdx.x >> 5;
    const int bx = blockIdx.x, by = blockIdx.y;
#pragma unroll
    for (int p = 0; p < 4; p++) {
        int r = r0 + p * 8;
        tile[r][c] = in[(size_t)(by * 32 + r) * DDD + bx * 32 + c];
    }
    __syncthreads();
#pragma unroll
    for (int p = 0; p < 4; p++) {
        int r = r0 + p * 8;
        out[(size_t)(bx * 32 + r) * ostride + by * 32 + c] = f2bf(tile[c][r]);
    }
}

// ---------------- MFMA GEMM (parallel phases), unchanged ----------------
template<bool AF32>
__global__ __launch_bounds__(256) void gemm_bf16_k(
    const void* __restrict__ Aptr, const u16* __restrict__ Bt,
    const float* __restrict__ bias, u16* __restrict__ C, int N)
{
    __shared__ u16 As[128 * 64];
    __shared__ u16 Bs[128 * 64];
    const int tid = threadIdx.x;
    const int row0 = blockIdx.x * 128;
    const int col0 = blockIdx.y * 128;
    const int lane = tid & 63, wid = tid >> 6;
    const int wr = wid >> 1, wc = wid & 1;
    const int lm = lane & 15, lq = lane >> 4;

    f32x4 acc[4][4];
#pragma unroll
    for (int i = 0; i < 4; i++)
#pragma unroll
        for (int j = 0; j < 4; j++) acc[i][j] = (f32x4){0.f, 0.f, 0.f, 0.f};

    for (int kc = 0; kc < 8; kc++) {
        const int k0 = kc * 64;
#pragma unroll
        for (int p = 0; p < 4; p++) {
            int g = p * 256 + tid;
            int row = g >> 3, j = g & 7;
            bf16x8 v;
            if (AF32) {
                const float* s = (const float*)Aptr + (size_t)(row0 + row) * DDD + k0 + j * 8;
                float4 a0 = *(const float4*)s;
                float4 a1 = *(const float4*)(s + 4);
                v[0] = (short)f2bf(a0.x); v[1] = (short)f2bf(a0.y);
                v[2] = (short)f2bf(a0.z); v[3] = (short)f2bf(a0.w);
                v[4] = (short)f2bf(a1.x); v[5] = (short)f2bf(a1.y);
                v[6] = (short)f2bf(a1.z); v[7] = (short)f2bf(a1.w);
            } else {
                v = *(const bf16x8*)((const u16*)Aptr + (size_t)(row0 + row) * DDD + k0 + j * 8);
            }
            *(bf16x8*)(As + row * 64 + ((j ^ (row & 7)) << 3)) = v;
        }
#pragma unroll
        for (int p = 0; p < 4; p++) {
            int g = p * 256 + tid;
            int n = g >> 3, j = g & 7;
            bf16x8 v = *(const bf16x8*)(Bt + (size_t)(col0 + n) * DDD + k0 + j * 8);
            *(bf16x8*)(Bs + n * 64 + ((j ^ (n & 7)) << 3)) = v;
        }
        __syncthreads();
#pragma unroll
        for (int ks = 0; ks < 2; ks++) {
            bf16x8 af[4], bfr[4];
#pragma unroll
            for (int i = 0; i < 4; i++) {
                int row = wr * 64 + i * 16 + lm;
                af[i] = *(const bf16x8*)(As + row * 64 + (((ks * 4 + lq) ^ (row & 7)) << 3));
            }
#pragma unroll
            for (int j = 0; j < 4; j++) {
                int n = wc * 64 + j * 16 + lm;
                bfr[j] = *(const bf16x8*)(Bs + n * 64 + (((ks * 4 + lq) ^ (n & 7)) << 3));
            }
#pragma unroll
            for (int i = 0; i < 4; i++)
#pragma unroll
                for (int j = 0; j < 4; j++)
                    acc[i][j] = __builtin_amdgcn_mfma_f32_16x16x32_bf16(af[i], bfr[j], acc[i][j], 0, 0, 0);
        }
        __syncthreads();
    }
#pragma unroll
    for (int j = 0; j < 4; j++) {
        int col = col0 + wc * 64 + j * 16 + lm;
        float bj = bias[col];
#pragma unroll
        for (int i = 0; i < 4; i++) {
            int rb = row0 + wr * 64 + i * 16 + lq * 4;
#pragma unroll
            for (int r = 0; r < 4; r++)
                C[(size_t)(rb + r) * N + col] = f2bf(acc[i][j][r] + bj);
        }
    }
}

// ---------------- LayerNorm + ReLU in-place on bf16 [M x 512] ----------------
__global__ __launch_bounds__(256) void ln_relu_k(
    u16* __restrict__ X, const float* __restrict__ gamma, const float* __restrict__ beta)
{
    const int tid = threadIdx.x;
    const int lane = tid & 63;
    const size_t row = (size_t)blockIdx.x * 4 + (tid >> 6);
    const int c0 = lane * 8;
    u16* px = X + row * DDD + c0;
    bf16x8 v = *(const bf16x8*)px;
    float f[8]; float s = 0.f, s2 = 0.f;
#pragma unroll
    for (int i = 0; i < 8; i++) { f[i] = bf2f((u16)v[i]); s += f[i]; s2 += f[i] * f[i]; }
#pragma unroll
    for (int off = 32; off; off >>= 1) { s += __shfl_xor(s, off); s2 += __shfl_xor(s2, off); }
    float mu = s * (1.f / (float)DDD);
    float rs = rsqrtf(s2 * (1.f / (float)DDD) - mu * mu + 1e-6f);
    float4 g0 = *(const float4*)(gamma + c0), g1 = *(const float4*)(gamma + c0 + 4);
    float4 b0 = *(const float4*)(beta + c0),  b1 = *(const float4*)(beta + c0 + 4);
    float gg[8] = {g0.x, g0.y, g0.z, g0.w, g1.x, g1.y, g1.z, g1.w};
    float bb[8] = {b0.x, b0.y, b0.z, b0.w, b1.x, b1.y, b1.z, b1.w};
    bf16x8 o;
#pragma unroll
    for (int i = 0; i < 8; i++) {
        float yv = (f[i] - mu) * rs * gg[i] + bb[i];
        o[i] = (short)f2bf(fmaxf(yv, 0.f));
    }
    *(bf16x8*)px = o;
}

// ---------------- logits ----------------
__global__ __launch_bounds__(256) void logits_k(
    const u16* __restrict__ AM, const float* __restrict__ Wa,
    const float* __restrict__ ba, const int* __restrict__ avail,
    float* __restrict__ out)
{
    __shared__ float xs[8][DDD];
    const int tid = threadIdx.x;
    const size_t row0 = (size_t)blockIdx.x * 8;
    for (int g = tid; g < 8 * 64; g += 256) {
        int r = g >> 6, c8 = (g & 63) * 8;
        bf16x8 v = *(const bf16x8*)(AM + (row0 + r) * DDD + c8);
#pragma unroll
        for (int i = 0; i < 8; i++) xs[r][c8 + i] = bf2f((u16)v[i]);
    }
    __syncthreads();
    const int r = tid >> 5, a = tid & 31;
    float acc = 0.f;
    for (int k = 0; k < DDD; k += 4) {
        float4 xv = *(const float4*)&xs[r][k];
        acc = fmaf(xv.x, Wa[(k + 0) * ACT + a], acc);
        acc = fmaf(xv.y, Wa[(k + 1) * ACT + a], acc);
        acc = fmaf(xv.z, Wa[(k + 2) * ACT + a], acc);
        acc = fmaf(xv.w, Wa[(k + 3) * ACT + a], acc);
    }
    size_t o = (row0 + r) * ACT + a;
    float v = acc + ba[a];
    if (avail[o] == 0) v -= 1e10f;
    out[o] = v;
}

// ---------------- list building ----------------
// key: 0 = done rows (h==0, skipH), 1 = t0 rows (h from `hidden`),
//      d+1 = depth-d rows otherwise. Parent key strictly < child key.
__global__ __launch_bounds__(256) void depth_build_k(
    const int* __restrict__ dones,
    int* __restrict__ keyA, int* __restrict__ pidxA,
    int* __restrict__ counts, int* __restrict__ maxk)
{
    __shared__ int lc[512];
    __shared__ int lmax;
    const int b = threadIdx.x;
    lc[b] = 0; lc[b + 256] = 0;
    if (b == 0) lmax = 0;
    __syncthreads();
    int dprev = 0, mx = 0;
    for (int t = 0; t < TTT; t++) {
        int pos = t * BBB + b;
        int d, pi, k;
        if (dones[pos] != 0)       { d = 0; pi = -1;       k = 0; }
        else if (t == 0)           { d = 0; pi = -2 - b;   k = 1; }
        else                       { d = dprev + 1; pi = pos - BBB; k = d + 1; }
        keyA[pos] = k; pidxA[pos] = pi;
        atomicAdd(&lc[k], 1);
        mx = max(mx, k);
        dprev = d;
    }
    atomicMax(&lmax, mx);
    __syncthreads();
    counts[b] = lc[b];
    counts[b + 256] = lc[b + 256];
    if (b == 0) *maxk = lmax;
}

// prefix scan + tail start (smallest k such that all k' >= k have counts <= 64)
__global__ void scan_k(const int* __restrict__ counts, int* __restrict__ offs,
                       int* __restrict__ tailK)
{
    if (threadIdx.x == 0) {
        int s = 0, tk = 0;
        for (int i = 0; i < 512; i++) {
            offs[i] = s; s += counts[i];
            if (counts[i] > 64) tk = i + 1;
        }
        *tailK = tk;
    }
}

__global__ __launch_bounds__(256) void scatter_k(
    const int* __restrict__ keyA, const int* __restrict__ offs,
    int* __restrict__ cursor, int* __restrict__ list)
{
    __shared__ int lcnt[512];
    __shared__ int lbase[512];
    const int tid = threadIdx.x;
    lcnt[tid] = 0; lcnt[tid + 256] = 0;
    __syncthreads();
    int pos = blockIdx.x * 256 + tid;
    int k = keyA[pos];
    int rank = atomicAdd(&lcnt[k], 1);
    __syncthreads();
    for (int q = tid; q < 512; q += 256) {
        int c = lcnt[q];
        lbase[q] = c ? atomicAdd(&cursor[q], c) : 0;
    }
    __syncthreads();
    list[offs[k] + lbase[k] + rank] = pos;
}

// ---------------- rep-only-fence grid barrier ----------------
// Arrival: RELAXED fetch_add on per-XCD counter (no fence). The LAST arriver
// per XCD does ONE __threadfence (wbl2 covers all co-XCD blocks: L1 is
// write-through and their stores were vmcnt-drained at __syncthreads), then
// joins the 8-rep global barrier (ACQ_REL, R5 kind). Wake: leaders spin
// RELAXED then one ACQUIRE (invalidate). Counter-reset-before-release
// ordering identical to the R5-proven barrier.
__device__ inline void fat_barrier(int* xcdCnt, int* xcdGen, int* gCnt, int* gGen,
                                   int e, int nxb)
{
    __syncthreads();   // drains this block's vmem (stores reach XCD L2)
    if (threadIdx.x == 0) {
        int* xc = xcdCnt + e * 32;
        int* xg = xcdGen + e * 32;
        int gx = AL_RLX(xg);
        int a = __hip_atomic_fetch_add(xc, 1, __ATOMIC_RELAXED, __HIP_MEMORY_SCOPE_AGENT);
        if (a == nxb - 1) {
            // last arriver of this XCD: publish the whole XCD's writes (1 wbl2)
            __threadfence();
            __hip_atomic_store(xc, 0, __ATOMIC_RELAXED, __HIP_MEMORY_SCOPE_AGENT);
            int gg = AL_RLX(gGen);
            int b = __hip_atomic_fetch_add(gCnt, 1, __ATOMIC_ACQ_REL, __HIP_MEMORY_SCOPE_AGENT);
            if (b == 7) {
                __hip_atomic_store(gCnt, 0, __ATOMIC_RELAXED, __HIP_MEMORY_SCOPE_AGENT);
                __hip_atomic_store(gGen, gg + 1, __ATOMIC_RELEASE, __HIP_MEMORY_SCOPE_AGENT);
            } else {
                while (AL_RLX(gGen) == gg) __builtin_amdgcn_s_sleep(2);
                (void)AL_ACQ(gGen);
            }
            __hip_atomic_store(xg, gx + 1, __ATOMIC_RELEASE, __HIP_MEMORY_SCOPE_AGENT);
        } else {
            while (AL_RLX(xg) == gx) __builtin_amdgcn_s_sleep(2);
            (void)AL_ACQ(xg);   // invalidate: see other XCDs' Y
        }
    }
    __syncthreads();
}

// ---------------- small-group barrier (R5 verbatim pattern, n participants) ----
__device__ inline void grid_barrier(int* cnt, int* gen, int nblk)
{
    __syncthreads();
    if (threadIdx.x == 0) {
        __threadfence();
        int g = AL_RLX(gen);
        int a = __hip_atomic_fetch_add(cnt, 1, __ATOMIC_ACQ_REL, __HIP_MEMORY_SCOPE_AGENT);
        if (a == nblk - 1) {
            __hip_atomic_store(cnt, 0, __ATOMIC_RELAXED, __HIP_MEMORY_SCOPE_AGENT);
            __hip_atomic_store(gen, g + 1, __ATOMIC_RELEASE, __HIP_MEMORY_SCOPE_AGENT);
        } else {
            while (AL_RLX(gen) == g) __builtin_amdgcn_s_sleep(2);
            (void)AL_ACQ(gen);
        }
        __threadfence();
    }
    __syncthreads();
}

// ---------------- GRU job body (R8 verbatim) ----------------
template<bool YF32>
__device__ __forceinline__ void gru_job(
    const u16* __restrict__ E, const float* __restrict__ hidden,
    const u16* __restrict__ Wstk, const float* __restrict__ bi,
    const float* __restrict__ bhn,
    const int* __restrict__ list, const int* __restrict__ pidxA,
    void* __restrict__ Yv,
    int off, int nd, int rt, int panel,
    u16* As, int* posL, int* pidxL, int* sAnyH)
{
    const int tid = threadIdx.x;
    const int w = tid >> 6, lane = tid & 63;
    const int lm = lane & 15, lq = lane >> 4;

    bool hasH = false;
    if (tid < 64) {
        int idx = rt * 64 + tid;
        int p = (idx < nd) ? list[off + idx] : -1;
        int pi = (p >= 0) ? pidxA[p] : -1;
        posL[tid] = p;
        pidxL[tid] = pi;
        hasH = (p >= 0) && (pi != -1);
        unsigned long long m = __ballot(hasH);
        if (tid == 0) *sAnyH = (m != 0ULL);
    }
    __syncthreads();
    const bool skipH = !(*sAnyH);

    f32x4 a01[4][4], aX[4][2], aH[4][2];
#pragma unroll
    for (int mt = 0; mt < 4; mt++) {
#pragma unroll
        for (int q = 0; q < 4; q++) a01[mt][q] = (f32x4){0.f, 0.f, 0.f, 0.f};
#pragma unroll
        for (int q = 0; q < 2; q++) {
            aX[mt][q] = (f32x4){0.f, 0.f, 0.f, 0.f};
            aH[mt][q] = (f32x4){0.f, 0.f, 0.f, 0.f};
        }
    }

    const int cb = panel * 128 + w * 32;
    const u16* wp[6];
#pragma unroll
    for (int ct = 0; ct < 6; ct++) {
        int gate = ct >> 1;
        int nglob = gate * 512 + cb + ((ct & 1) << 4) + lm;
        wp[ct] = Wstk + (size_t)nglob * 1024 + lq * 8;
    }

    const int nkc = skipH ? 2 : 4;
    for (int kc = 0; kc < nkc; kc++) {
        // stage A chunk: 64 rows x 256 K (gathered rows)
#pragma unroll
        for (int it = 0; it < 8; it++) {
            int g = it * 256 + tid;
            int row = g >> 5, jg = g & 31;
            int kglob = kc * 256 + jg * 8;
            bf16x8 v = (bf16x8){0, 0, 0, 0, 0, 0, 0, 0};
            int p = posL[row];
            if (p >= 0) {
                if (kglob < 512) {
                    v = *(const bf16x8*)(E + (size_t)p * DDD + kglob);
                } else {
                    int k2 = kglob - 512;
                    int pi = pidxL[row];
                    if (pi >= 0) {
                        if (YF32) {
                            const float* s = (const float*)Yv + (size_t)pi * DDD + k2;
                            float4 a0 = *(const float4*)s;
                            float4 a1 = *(const float4*)(s + 4);
                            v[0] = (short)f2bf(a0.x); v[1] = (short)f2bf(a0.y);
                            v[2] = (short)f2bf(a0.z); v[3] = (short)f2bf(a0.w);
                            v[4] = (short)f2bf(a1.x); v[5] = (short)f2bf(a1.y);
                            v[6] = (short)f2bf(a1.z); v[7] = (short)f2bf(a1.w);
                        } else {
                            v = *(const bf16x8*)((const u16*)Yv + (size_t)pi * DDD + k2);
                        }
                    } else if (pi <= -2) {
                        const float* s = hidden + (size_t)(-pi - 2) * DDD + k2;
                        float4 a0 = *(const float4*)s;
                        float4 a1 = *(const float4*)(s + 4);
                        v[0] = (short)f2bf(a0.x); v[1] = (short)f2bf(a0.y);
                        v[2] = (short)f2bf(a0.z); v[3] = (short)f2bf(a0.w);
                        v[4] = (short)f2bf(a1.x); v[5] = (short)f2bf(a1.y);
                        v[6] = (short)f2bf(a1.z); v[7] = (short)f2bf(a1.w);
                    }
                }
            }
            *(bf16x8*)(As + row * 256 + ((jg ^ (row & 31)) << 3)) = v;
        }
        __syncthreads();

        const bool xpart = (kc < 2);
        const int kgb = kc * 256;
        bf16x8 bfA[6], bfB[6];

#define LOADW(B, KG) \
    _Pragma("unroll") \
    for (int ct = 0; ct < 6; ct++) B[ct] = *(const bf16x8*)(wp[ct] + (KG));

#define COMPW(B, S) \
    _Pragma("unroll") \
    for (int mt = 0; mt < 4; mt++) { \
        int row = mt * 16 + lm; \
        int jgr = (S) * 4 + lq; \
        bf16x8 af = *(const bf16x8*)(As + row * 256 + ((jgr ^ (row & 31)) << 3)); \
        a01[mt][0] = __builtin_amdgcn_mfma_f32_16x16x32_bf16(af, B[0], a01[mt][0], 0, 0, 0); \
        a01[mt][1] = __builtin_amdgcn_mfma_f32_16x16x32_bf16(af, B[1], a01[mt][1], 0, 0, 0); \
        a01[mt][2] = __builtin_amdgcn_mfma_f32_16x16x32_bf16(af, B[2], a01[mt][2], 0, 0, 0); \
        a01[mt][3] = __builtin_amdgcn_mfma_f32_16x16x32_bf16(af, B[3], a01[mt][3], 0, 0, 0); \
        if (xpart) { \
            aX[mt][0] = __builtin_amdgcn_mfma_f32_16x16x32_bf16(af, B[4], aX[mt][0], 0, 0, 0); \
            aX[mt][1] = __builtin_amdgcn_mfma_f32_16x16x32_bf16(af, B[5], aX[mt][1], 0, 0, 0); \
        } else { \
            aH[mt][0] = __builtin_amdgcn_mfma_f32_16x16x32_bf16(af, B[4], aH[mt][0], 0, 0, 0); \
            aH[mt][1] = __builtin_amdgcn_mfma_f32_16x16x32_bf16(af, B[5], aH[mt][1], 0, 0, 0); \
        } \
    }

        LOADW(bfA, kgb + 0 * 32);
#pragma unroll
        for (int sp = 0; sp < 4; sp++) {
            const int s0 = sp * 2, s1 = sp * 2 + 1;
            LOADW(bfB, kgb + s1 * 32);
            COMPW(bfA, s0);
            if (sp < 3) { LOADW(bfA, kgb + (s1 + 1) * 32); }
            COMPW(bfB, s1);
        }
#undef LOADW
#undef COMPW
        __syncthreads();
    }

    // wave-local gate combine + Y write
#pragma unroll
    for (int mt = 0; mt < 4; mt++) {
#pragma unroll
        for (int r = 0; r < 4; r++) {
            int row = mt * 16 + lq * 4 + r;
            int p = posL[row];
            if (p < 0) continue;
            int pi = pidxL[row];
#pragma unroll
            for (int ct = 0; ct < 2; ct++) {
                int cglob = cb + ct * 16 + lm;
                float rpre = a01[mt][ct][r]     + bi[cglob];
                float zpre = a01[mt][2 + ct][r] + bi[512 + cglob];
                float xn   = aX[mt][ct][r]      + bi[1024 + cglob];
                float hn   = aH[mt][ct][r]      + bhn[cglob];
                float rg = 1.f / (1.f + __expf(-rpre));
                float zg = 1.f / (1.f + __expf(-zpre));
                float targ = xn + rg * hn;
                float t2 = __expf(-2.f * fabsf(targ));
                float ng = copysignf((1.f - t2) / (1.f + t2), targ);
                float hp = 0.f;
                if (pi >= 0)
                    hp = YF32 ? ((const float*)Yv)[(size_t)pi * DDD + cglob]
                              : bf2f(((const u16*)Yv)[(size_t)pi * DDD + cglob]);
                else if (pi <= -2)
                    hp = hidden[(size_t)(-pi - 2) * DDD + cglob];
                float hnew = (1.f - zg) * ng + zg * hp;
                if (YF32) ((float*)Yv)[(size_t)p * DDD + cglob] = hnew;
                else      ((u16*)Yv)[(size_t)p * DDD + cglob] = f2bf(hnew);
            }
        }
    }
    __syncthreads();   // protect posL/As for next job
}

// ---------------- round-based GRU: fat rounds + 4-block tail ----------------
template<bool YF32>
__global__ __launch_bounds__(256, 2) void gru_depth_k(
    const u16* __restrict__ E, const float* __restrict__ hidden,
    const u16* __restrict__ Wstk, const float* __restrict__ bi,
    const float* __restrict__ bhn,
    const int* __restrict__ list, const int* __restrict__ offs,
    const int* __restrict__ counts, const int* __restrict__ maxk,
    const int* __restrict__ tailK, const int* __restrict__ pidxA,
    void* __restrict__ Yv, float* __restrict__ hid_out,
    int* __restrict__ xcdCnt, int* __restrict__ xcdGen,
    int* __restrict__ gCnt, int* __restrict__ gGen,
    int* __restrict__ tCnt, int* __restrict__ tGen)
{
    __shared__ u16 As[64 * 256];         // 32 KB
    __shared__ int posL[64], pidxL[64];
    __shared__ int sAnyH;
    const int tid = threadIdx.x;
    const int nblk = gridDim.x;
    const int e   = blockIdx.x & 7;      // XCD id (round-robin dispatch)
    const int xb  = blockIdx.x >> 3;     // block index within XCD
    const int nxb = nblk >> 3;           // blocks per XCD

    const int MK = *maxk;
    const int TK = *tailK;               // all k >= TK have counts <= 64 (TK >= 2)
    const int lastFat = (MK < TK - 1) ? MK : (TK - 1);

    // ---- fat rounds: full grid, XCD-grouped jobs, rep-only-fence barrier ----
    for (int k = 0; k <= lastFat; k++) {
        const int nd = counts[k];
        const int off = offs[k];
        const int ntiles = (nd + 63) >> 6;
        const int ntl = (ntiles - e + 7) >> 3;   // tiles with rt%8==e
        const int njl = (ntl > 0) ? (ntl << 2) : 0;
        for (int lj = xb; lj < njl; lj += nxb) {
            const int rt = ((lj >> 2) << 3) + e;
            const int panel = lj & 3;
            gru_job<YF32>(E, hidden, Wstk, bi, bhn, list, pidxA, Yv,
                          off, nd, rt, panel, As, posL, pidxL, &sAnyH);
        }
        fat_barrier(xcdCnt, xcdGen, gCnt, gGen, e, nxb);
    }

    // ---- tail rounds: 4 blocks on XCD 0 (blockIdx 0,8,16,24), others exit ----
    const bool isTail = (e == 0) && (xb < 4);
    if (!isTail) return;

    for (int k = TK; k <= MK; k++) {
        const int nd = counts[k];
        const int off = offs[k];
        gru_job<YF32>(E, hidden, Wstk, bi, bhn, list, pidxA, Yv,
                      off, nd, 0, xb, As, posL, pidxL, &sAnyH);
        grid_barrier(tCnt, tGen, 4);
    }

    // final hidden: out[b*512+c] = Y[(255*256+b)*512+c]  (4 tail blocks)
    for (int i = xb * 256 + tid; i < BBB * DDD; i += 1024) {
        int b = i >> 9, c = i & 511;
        size_t yi = (size_t)(65280 + b) * DDD + c;
        hid_out[i] = YF32 ? ((const float*)Yv)[yi] : bf2f(((const u16*)Yv)[yi]);
    }
}

extern "C" void kernel_launch(void* const* d_in, const int* in_sizes, int n_in,
                              void* d_out, int out_size, void* d_ws, size_t ws_size,
                              hipStream_t stream)
{
    const float* hidden = (const float*)d_in[0];
    const float* obs    = (const float*)d_in[1];
    const int*   dones  = (const int*)d_in[2];
    const int*   avail  = (const int*)d_in[3];
    const float* Wm     = (const float*)d_in[4];
    const float* bm     = (const float*)d_in[5];
    const float* lns    = (const float*)d_in[6];
    const float* lnb    = (const float*)d_in[7];
    const float* Wi     = (const float*)d_in[8];
    const float* bi     = (const float*)d_in[9];
    const float* Wh     = (const float*)d_in[10];
    const float* bhn    = (const float*)d_in[11];
    const float* Wo     = (const float*)d_in[12];
    const float* bo     = (const float*)d_in[13];
    const float* ln2s   = (const float*)d_in[14];
    const float* ln2b   = (const float*)d_in[15];
    const float* Wa     = (const float*)d_in[16];
    const float* ba     = (const float*)d_in[17];
    float* out = (float*)d_out;

    // workspace layout
    char* w = (char*)d_ws;
    u16* Wstk = (u16*)w;  w += (size_t)1536 * 1024 * 2;      // 3 MB
    u16* WmT  = (u16*)w;  w += (size_t)3 * DDD * DDD * 2;
    u16* WoT  = (u16*)w;  w += (size_t)DDD * DDD * 2;
    int* meta = (int*)w;  w += 16384;
    int* counts = meta;              // 512
    int* offs   = meta + 512;        // 512
    int* cursor = meta + 1024;       // 512
    int* maxk   = meta + 1536;
    int* tailK  = meta + 1552;
    int* xcdCnt = meta + 1600;       // 8 x stride-32
    int* xcdGen = meta + 1856;       // 8 x stride-32
    int* gCnt   = meta + 2112;
    int* gGen   = meta + 2144;
    int* tCnt   = meta + 2176;
    int* tGen   = meta + 2208;
    int* keyA   = (int*)w;  w += (size_t)MMM * 4;
    int* pidxA  = (int*)w;  w += (size_t)MMM * 4;
    int* list   = (int*)w;  w += (size_t)MMM * 4;
    u16* P = (u16*)w;       w += (size_t)MMM * DDD * 2;      // 64 MB
    void* Yv = (void*)w;
    const size_t base = (size_t)(w - (char*)d_ws);
    const bool yf32 = (ws_size >= base + (size_t)MMM * DDD * 4);

    // prep: weight transposes + meta zero
    dim3 tgrid(16, 16);
    for (int l = 0; l < 3; l++)
        transpose_cvt_k<<<tgrid, 256, 0, stream>>>(Wm + (size_t)l * DDD * DDD, WmT + (size_t)l * DDD * DDD, DDD);
    transpose_cvt_k<<<tgrid, 256, 0, stream>>>(Wo, WoT, DDD);
    for (int g = 0; g < 3; g++) {
        transpose_cvt_k<<<tgrid, 256, 0, stream>>>(Wi + (size_t)g * DDD * DDD, Wstk + (size_t)g * 512 * 1024, 1024);
        transpose_cvt_k<<<tgrid, 256, 0, stream>>>(Wh + (size_t)g * DDD * DDD, Wstk + (size_t)g * 512 * 1024 + 512, 1024);
    }
    hipMemsetAsync(meta, 0, 16384, stream);

    // key lists (done-first within depth 0) + tail start
    depth_build_k<<<1, 256, 0, stream>>>(dones, keyA, pidxA, counts, maxk);
    scan_k<<<1, 64, 0, stream>>>(counts, offs, tailK);
    scatter_k<<<MMM / 256, 256, 0, stream>>>(keyA, offs, cursor, list);

    // encoder: obs -> P -> Y -> P
    u16* Yq = (u16*)Yv;
    gemm_bf16_k<true><<<dim3(MMM / 128, 4), 256, 0, stream>>>(obs, WmT, bm, P, DDD);
    ln_relu_k<<<dim3(MMM / 4), 256, 0, stream>>>(P, lns, lnb);
    gemm_bf16_k<false><<<dim3(MMM / 128, 4), 256, 0, stream>>>(P, WmT + (size_t)DDD * DDD, bm + DDD, Yq, DDD);
    ln_relu_k<<<dim3(MMM / 4), 256, 0, stream>>>(Yq, lns + DDD, lnb + DDD);
    gemm_bf16_k<false><<<dim3(MMM / 128, 4), 256, 0, stream>>>(Yq, WmT + (size_t)2 * DDD * DDD, bm + 2 * DDD, P, DDD);
    ln_relu_k<<<dim3(MMM / 4), 256, 0, stream>>>(P, lns + 2 * DDD, lnb + 2 * DDD);

    // persistent-block GRU; grid sized to guaranteed co-residency
    {
        const void* fptr = yf32 ? (const void*)gru_depth_k<true>
                                : (const void*)gru_depth_k<false>;
        int occ = 0;
        hipError_t err = hipOccupancyMaxActiveBlocksPerMultiprocessor(&occ, fptr, 256, 0);
        if (err != hipSuccess || occ < 1) occ = 2;
        if (occ > 4) occ = 4;
        dim3 grid(occ * 256);
        if (yf32)
            gru_depth_k<true><<<grid, 256, 0, stream>>>(
                P, hidden, Wstk, bi, bhn, list, offs, counts, maxk, tailK, pidxA,
                Yv, out, xcdCnt, xcdGen, gCnt, gGen, tCnt, tGen);
        else
            gru_depth_k<false><<<grid, 256, 0, stream>>>(
                P, hidden, Wstk, bi, bhn, list, offs, counts, maxk, tailK, pidxA,
                Yv, out, xcdCnt, xcdGen, gCnt, gGen, tCnt, tGen);
    }

    // head: Y -> P, LN, logits
    if (yf32)
        gemm_bf16_k<true><<<dim3(MMM / 128, 4), 256, 0, stream>>>(Yv, WoT, bo, P, DDD);
    else
        gemm_bf16_k<false><<<dim3(MMM / 128, 4), 256, 0, stream>>>(Yv, WoT, bo, P, DDD);
    ln_relu_k<<<dim3(MMM / 4), 256, 0, stream>>>(P, ln2s, ln2b);
    logits_k<<<dim3(MMM / 8), 256, 0, stream>>>(P, Wa, ba, avail, out + BBB * DDD);
}

// Round 7
// 1880.723 us; speedup vs baseline: 1.2655x; 1.0669x over previous
//
#include <hip/hip_runtime.h>
#include <hip/hip_bf16.h>
#include <math.h>

// PPOActorRNN on MI355X — round 11: XCD-sharded GRU, zero-fence rounds.
// R6 lesson: any cross-XCD-coherent barrier costs ~40-60us/round (wbl2 drain
// of dirty L2 + full L2 inv + LLC refetch of W/E) regardless of how few
// leaders fence (wbl2 cost is data-proportional). Fix: make the recurrence
// XCD-local. Batch columns b are sharded 32-per-XCD (e = blockIdx&7,
// cols 32e..32e+31). Y never crosses XCDs:
//  - plain Y stores / plain Y loads, visible via the SHARED per-XCD L2
//    (L1-stale impossible: every Y line is written once then read).
//  - per-XCD barrier: monotonic RELAXED fetch_add + RELAXED spin on the
//    same address (publication IS the RMW; no release stores, no resets,
//    no fences, no invalidates). Deadlock-free: per-XCD round count is
//    data-independent; counter monotonic.
//  - XCDs run fully asynchronously; no global barrier; each XCD copies its
//    own columns' final hidden after its last round.
// W/E stay cache-resident the whole kernel. Job body = R6 verbatim.

#define TTT 256
#define BBB 256
#define DDD 512
#define ACT 32
#define MMM (TTT*BBB)

typedef short bf16x8 __attribute__((ext_vector_type(8)));
typedef float f32x4 __attribute__((ext_vector_type(4)));
typedef unsigned short u16;

__device__ inline u16 f2bf(float f) {
    unsigned int u = __float_as_uint(f);
    u += 0x7fffu + ((u >> 16) & 1u);
    return (u16)(u >> 16);
}
__device__ inline float bf2f(u16 h) { return __uint_as_float(((unsigned int)h) << 16); }

#define AL_RLX(p)  __hip_atomic_load((p), __ATOMIC_RELAXED, __HIP_MEMORY_SCOPE_AGENT)

// ---------------- transpose + cvt: out[n*ostride + k] = bf16(in[k*512 + n]) ----
__global__ __launch_bounds__(256) void transpose_cvt_k(
    const float* __restrict__ in, u16* __restrict__ out, int ostride)
{
    __shared__ float tile[32][33];
    const int c = threadIdx.x & 31;
    const int r0 = threadIdx.x >> 5;
    const int bx = blockIdx.x, by = blockIdx.y;
#pragma unroll
    for (int p = 0; p < 4; p++) {
        int r = r0 + p * 8;
        tile[r][c] = in[(size_t)(by * 32 + r) * DDD + bx * 32 + c];
    }
    __syncthreads();
#pragma unroll
    for (int p = 0; p < 4; p++) {
        int r = r0 + p * 8;
        out[(size_t)(bx * 32 + r) * ostride + by * 32 + c] = f2bf(tile[c][r]);
    }
}

// ---------------- MFMA GEMM (parallel phases), unchanged ----------------
template<bool AF32>
__global__ __launch_bounds__(256) void gemm_bf16_k(
    const void* __restrict__ Aptr, const u16* __restrict__ Bt,
    const float* __restrict__ bias, u16* __restrict__ C, int N)
{
    __shared__ u16 As[128 * 64];
    __shared__ u16 Bs[128 * 64];
    const int tid = threadIdx.x;
    const int row0 = blockIdx.x * 128;
    const int col0 = blockIdx.y * 128;
    const int lane = tid & 63, wid = tid >> 6;
    const int wr = wid >> 1, wc = wid & 1;
    const int lm = lane & 15, lq = lane >> 4;

    f32x4 acc[4][4];
#pragma unroll
    for (int i = 0; i < 4; i++)
#pragma unroll
        for (int j = 0; j < 4; j++) acc[i][j] = (f32x4){0.f, 0.f, 0.f, 0.f};

    for (int kc = 0; kc < 8; kc++) {
        const int k0 = kc * 64;
#pragma unroll
        for (int p = 0; p < 4; p++) {
            int g = p * 256 + tid;
            int row = g >> 3, j = g & 7;
            bf16x8 v;
            if (AF32) {
                const float* s = (const float*)Aptr + (size_t)(row0 + row) * DDD + k0 + j * 8;
                float4 a0 = *(const float4*)s;
                float4 a1 = *(const float4*)(s + 4);
                v[0] = (short)f2bf(a0.x); v[1] = (short)f2bf(a0.y);
                v[2] = (short)f2bf(a0.z); v[3] = (short)f2bf(a0.w);
                v[4] = (short)f2bf(a1.x); v[5] = (short)f2bf(a1.y);
                v[6] = (short)f2bf(a1.z); v[7] = (short)f2bf(a1.w);
            } else {
                v = *(const bf16x8*)((const u16*)Aptr + (size_t)(row0 + row) * DDD + k0 + j * 8);
            }
            *(bf16x8*)(As + row * 64 + ((j ^ (row & 7)) << 3)) = v;
        }
#pragma unroll
        for (int p = 0; p < 4; p++) {
            int g = p * 256 + tid;
            int n = g >> 3, j = g & 7;
            bf16x8 v = *(const bf16x8*)(Bt + (size_t)(col0 + n) * DDD + k0 + j * 8);
            *(bf16x8*)(Bs + n * 64 + ((j ^ (n & 7)) << 3)) = v;
        }
        __syncthreads();
#pragma unroll
        for (int ks = 0; ks < 2; ks++) {
            bf16x8 af[4], bfr[4];
#pragma unroll
            for (int i = 0; i < 4; i++) {
                int row = wr * 64 + i * 16 + lm;
                af[i] = *(const bf16x8*)(As + row * 64 + (((ks * 4 + lq) ^ (row & 7)) << 3));
            }
#pragma unroll
            for (int j = 0; j < 4; j++) {
                int n = wc * 64 + j * 16 + lm;
                bfr[j] = *(const bf16x8*)(Bs + n * 64 + (((ks * 4 + lq) ^ (n & 7)) << 3));
            }
#pragma unroll
            for (int i = 0; i < 4; i++)
#pragma unroll
                for (int j = 0; j < 4; j++)
                    acc[i][j] = __builtin_amdgcn_mfma_f32_16x16x32_bf16(af[i], bfr[j], acc[i][j], 0, 0, 0);
        }
        __syncthreads();
    }
#pragma unroll
    for (int j = 0; j < 4; j++) {
        int col = col0 + wc * 64 + j * 16 + lm;
        float bj = bias[col];
#pragma unroll
        for (int i = 0; i < 4; i++) {
            int rb = row0 + wr * 64 + i * 16 + lq * 4;
#pragma unroll
            for (int r = 0; r < 4; r++)
                C[(size_t)(rb + r) * N + col] = f2bf(acc[i][j][r] + bj);
        }
    }
}

// ---------------- LayerNorm + ReLU in-place on bf16 [M x 512] ----------------
__global__ __launch_bounds__(256) void ln_relu_k(
    u16* __restrict__ X, const float* __restrict__ gamma, const float* __restrict__ beta)
{
    const int tid = threadIdx.x;
    const int lane = tid & 63;
    const size_t row = (size_t)blockIdx.x * 4 + (tid >> 6);
    const int c0 = lane * 8;
    u16* px = X + row * DDD + c0;
    bf16x8 v = *(const bf16x8*)px;
    float f[8]; float s = 0.f, s2 = 0.f;
#pragma unroll
    for (int i = 0; i < 8; i++) { f[i] = bf2f((u16)v[i]); s += f[i]; s2 += f[i] * f[i]; }
#pragma unroll
    for (int off = 32; off; off >>= 1) { s += __shfl_xor(s, off); s2 += __shfl_xor(s2, off); }
    float mu = s * (1.f / (float)DDD);
    float rs = rsqrtf(s2 * (1.f / (float)DDD) - mu * mu + 1e-6f);
    float4 g0 = *(const float4*)(gamma + c0), g1 = *(const float4*)(gamma + c0 + 4);
    float4 b0 = *(const float4*)(beta + c0),  b1 = *(const float4*)(beta + c0 + 4);
    float gg[8] = {g0.x, g0.y, g0.z, g0.w, g1.x, g1.y, g1.z, g1.w};
    float bb[8] = {b0.x, b0.y, b0.z, b0.w, b1.x, b1.y, b1.z, b1.w};
    bf16x8 o;
#pragma unroll
    for (int i = 0; i < 8; i++) {
        float yv = (f[i] - mu) * rs * gg[i] + bb[i];
        o[i] = (short)f2bf(fmaxf(yv, 0.f));
    }
    *(bf16x8*)px = o;
}

// ---------------- logits ----------------
__global__ __launch_bounds__(256) void logits_k(
    const u16* __restrict__ AM, const float* __restrict__ Wa,
    const float* __restrict__ ba, const int* __restrict__ avail,
    float* __restrict__ out)
{
    __shared__ float xs[8][DDD];
    const int tid = threadIdx.x;
    const size_t row0 = (size_t)blockIdx.x * 8;
    for (int g = tid; g < 8 * 64; g += 256) {
        int r = g >> 6, c8 = (g & 63) * 8;
        bf16x8 v = *(const bf16x8*)(AM + (row0 + r) * DDD + c8);
#pragma unroll
        for (int i = 0; i < 8; i++) xs[r][c8 + i] = bf2f((u16)v[i]);
    }
    __syncthreads();
    const int r = tid >> 5, a = tid & 31;
    float acc = 0.f;
    for (int k = 0; k < DDD; k += 4) {
        float4 xv = *(const float4*)&xs[r][k];
        acc = fmaf(xv.x, Wa[(k + 0) * ACT + a], acc);
        acc = fmaf(xv.y, Wa[(k + 1) * ACT + a], acc);
        acc = fmaf(xv.z, Wa[(k + 2) * ACT + a], acc);
        acc = fmaf(xv.w, Wa[(k + 3) * ACT + a], acc);
    }
    size_t o = (row0 + r) * ACT + a;
    float v = acc + ba[a];
    if (avail[o] == 0) v -= 1e10f;
    out[o] = v;
}

// ---------------- list building (per-XCD buckets) ----------------
// column b -> shard e = b>>5. key: 0 = done rows (skipH), 1 = t0 rows,
// d+1 = depth-d rows. Parent key strictly < child key, same shard.
__global__ __launch_bounds__(256) void depth_build_k(
    const int* __restrict__ dones,
    int* __restrict__ keyA, int* __restrict__ pidxA,
    int* __restrict__ counts, int* __restrict__ maxk)
{
    __shared__ int lc[8 * 512];
    __shared__ int lmax[8];
    const int b = threadIdx.x;
    const int e = b >> 5;
    for (int i = b; i < 8 * 512; i += 256) lc[i] = 0;
    if (b < 8) lmax[b] = 0;
    __syncthreads();
    int dprev = 0, mx = 0;
    for (int t = 0; t < TTT; t++) {
        int pos = t * BBB + b;
        int d, pi, k;
        if (dones[pos] != 0)       { d = 0; pi = -1;       k = 0; }
        else if (t == 0)           { d = 0; pi = -2 - b;   k = 1; }
        else                       { d = dprev + 1; pi = pos - BBB; k = d + 1; }
        keyA[pos] = k; pidxA[pos] = pi;
        atomicAdd(&lc[e * 512 + k], 1);
        mx = max(mx, k);
        dprev = d;
    }
    atomicMax(&lmax[e], mx);
    __syncthreads();
    for (int i = b; i < 8 * 512; i += 256) counts[i] = lc[i];
    if (b < 8) maxk[b] = lmax[b];
}

__global__ void scan_k(const int* __restrict__ counts, int* __restrict__ offs)
{
    int e = threadIdx.x;
    if (e < 8) {
        int s = 0;
        for (int i = 0; i < 512; i++) { offs[e * 512 + i] = s; s += counts[e * 512 + i]; }
    }
}

__global__ __launch_bounds__(256) void scatter_k(
    const int* __restrict__ keyA, const int* __restrict__ offs,
    int* __restrict__ cursor, int* __restrict__ list)
{
    __shared__ int lcnt[8 * 512];
    __shared__ int lbase[8 * 512];
    const int tid = threadIdx.x;
    for (int i = tid; i < 8 * 512; i += 256) lcnt[i] = 0;
    __syncthreads();
    int pos = blockIdx.x * 256 + tid;
    int b = pos & 255;
    int e = b >> 5;
    int k = keyA[pos];
    int rank = atomicAdd(&lcnt[e * 512 + k], 1);
    __syncthreads();
    for (int q = tid; q < 8 * 512; q += 256) {
        int c = lcnt[q];
        lbase[q] = c ? atomicAdd(&cursor[q], c) : 0;
    }
    __syncthreads();
    list[e * 8192 + offs[e * 512 + k] + lbase[e * 512 + k] + rank] = pos;
}

// ---------------- GRU job body (R6 verbatim; plain Y access) ----------------
template<bool YF32>
__device__ __forceinline__ void gru_job(
    const u16* __restrict__ E, const float* __restrict__ hidden,
    const u16* __restrict__ Wstk, const float* __restrict__ bi,
    const float* __restrict__ bhn,
    const int* __restrict__ list, const int* __restrict__ pidxA,
    void* __restrict__ Yv,
    int off, int nd, int rt, int panel,
    u16* As, int* posL, int* pidxL, int* sAnyH)
{
    const int tid = threadIdx.x;
    const int w = tid >> 6, lane = tid & 63;
    const int lm = lane & 15, lq = lane >> 4;

    bool hasH = false;
    if (tid < 64) {
        int idx = rt * 64 + tid;
        int p = (idx < nd) ? list[off + idx] : -1;
        int pi = (p >= 0) ? pidxA[p] : -1;
        posL[tid] = p;
        pidxL[tid] = pi;
        hasH = (p >= 0) && (pi != -1);
        unsigned long long m = __ballot(hasH);
        if (tid == 0) *sAnyH = (m != 0ULL);
    }
    __syncthreads();
    const bool skipH = !(*sAnyH);

    f32x4 a01[4][4], aX[4][2], aH[4][2];
#pragma unroll
    for (int mt = 0; mt < 4; mt++) {
#pragma unroll
        for (int q = 0; q < 4; q++) a01[mt][q] = (f32x4){0.f, 0.f, 0.f, 0.f};
#pragma unroll
        for (int q = 0; q < 2; q++) {
            aX[mt][q] = (f32x4){0.f, 0.f, 0.f, 0.f};
            aH[mt][q] = (f32x4){0.f, 0.f, 0.f, 0.f};
        }
    }

    const int cb = panel * 128 + w * 32;
    const u16* wp[6];
#pragma unroll
    for (int ct = 0; ct < 6; ct++) {
        int gate = ct >> 1;
        int nglob = gate * 512 + cb + ((ct & 1) << 4) + lm;
        wp[ct] = Wstk + (size_t)nglob * 1024 + lq * 8;
    }

    const int nkc = skipH ? 2 : 4;
    for (int kc = 0; kc < nkc; kc++) {
        // stage A chunk: 64 rows x 256 K (gathered rows)
#pragma unroll
        for (int it = 0; it < 8; it++) {
            int g = it * 256 + tid;
            int row = g >> 5, jg = g & 31;
            int kglob = kc * 256 + jg * 8;
            bf16x8 v = (bf16x8){0, 0, 0, 0, 0, 0, 0, 0};
            int p = posL[row];
            if (p >= 0) {
                if (kglob < 512) {
                    v = *(const bf16x8*)(E + (size_t)p * DDD + kglob);
                } else {
                    int k2 = kglob - 512;
                    int pi = pidxL[row];
                    if (pi >= 0) {
                        if (YF32) {
                            const float* s = (const float*)Yv + (size_t)pi * DDD + k2;
                            float4 a0 = *(const float4*)s;
                            float4 a1 = *(const float4*)(s + 4);
                            v[0] = (short)f2bf(a0.x); v[1] = (short)f2bf(a0.y);
                            v[2] = (short)f2bf(a0.z); v[3] = (short)f2bf(a0.w);
                            v[4] = (short)f2bf(a1.x); v[5] = (short)f2bf(a1.y);
                            v[6] = (short)f2bf(a1.z); v[7] = (short)f2bf(a1.w);
                        } else {
                            v = *(const bf16x8*)((const u16*)Yv + (size_t)pi * DDD + k2);
                        }
                    } else if (pi <= -2) {
                        const float* s = hidden + (size_t)(-pi - 2) * DDD + k2;
                        float4 a0 = *(const float4*)s;
                        float4 a1 = *(const float4*)(s + 4);
                        v[0] = (short)f2bf(a0.x); v[1] = (short)f2bf(a0.y);
                        v[2] = (short)f2bf(a0.z); v[3] = (short)f2bf(a0.w);
                        v[4] = (short)f2bf(a1.x); v[5] = (short)f2bf(a1.y);
                        v[6] = (short)f2bf(a1.z); v[7] = (short)f2bf(a1.w);
                    }
                }
            }
            *(bf16x8*)(As + row * 256 + ((jg ^ (row & 31)) << 3)) = v;
        }
        __syncthreads();

        const bool xpart = (kc < 2);
        const int kgb = kc * 256;
        bf16x8 bfA[6], bfB[6];

#define LOADW(B, KG) \
    _Pragma("unroll") \
    for (int ct = 0; ct < 6; ct++) B[ct] = *(const bf16x8*)(wp[ct] + (KG));

#define COMPW(B, S) \
    _Pragma("unroll") \
    for (int mt = 0; mt < 4; mt++) { \
        int row = mt * 16 + lm; \
        int jgr = (S) * 4 + lq; \
        bf16x8 af = *(const bf16x8*)(As + row * 256 + ((jgr ^ (row & 31)) << 3)); \
        a01[mt][0] = __builtin_amdgcn_mfma_f32_16x16x32_bf16(af, B[0], a01[mt][0], 0, 0, 0); \
        a01[mt][1] = __builtin_amdgcn_mfma_f32_16x16x32_bf16(af, B[1], a01[mt][1], 0, 0, 0); \
        a01[mt][2] = __builtin_amdgcn_mfma_f32_16x16x32_bf16(af, B[2], a01[mt][2], 0, 0, 0); \
        a01[mt][3] = __builtin_amdgcn_mfma_f32_16x16x32_bf16(af, B[3], a01[mt][3], 0, 0, 0); \
        if (xpart) { \
            aX[mt][0] = __builtin_amdgcn_mfma_f32_16x16x32_bf16(af, B[4], aX[mt][0], 0, 0, 0); \
            aX[mt][1] = __builtin_amdgcn_mfma_f32_16x16x32_bf16(af, B[5], aX[mt][1], 0, 0, 0); \
        } else { \
            aH[mt][0] = __builtin_amdgcn_mfma_f32_16x16x32_bf16(af, B[4], aH[mt][0], 0, 0, 0); \
            aH[mt][1] = __builtin_amdgcn_mfma_f32_16x16x32_bf16(af, B[5], aH[mt][1], 0, 0, 0); \
        } \
    }

        LOADW(bfA, kgb + 0 * 32);
#pragma unroll
        for (int sp = 0; sp < 4; sp++) {
            const int s0 = sp * 2, s1 = sp * 2 + 1;
            LOADW(bfB, kgb + s1 * 32);
            COMPW(bfA, s0);
            if (sp < 3) { LOADW(bfA, kgb + (s1 + 1) * 32); }
            COMPW(bfB, s1);
        }
#undef LOADW
#undef COMPW
        __syncthreads();
    }

    // wave-local gate combine + Y write
#pragma unroll
    for (int mt = 0; mt < 4; mt++) {
#pragma unroll
        for (int r = 0; r < 4; r++) {
            int row = mt * 16 + lq * 4 + r;
            int p = posL[row];
            if (p < 0) continue;
            int pi = pidxL[row];
#pragma unroll
            for (int ct = 0; ct < 2; ct++) {
                int cglob = cb + ct * 16 + lm;
                float rpre = a01[mt][ct][r]     + bi[cglob];
                float zpre = a01[mt][2 + ct][r] + bi[512 + cglob];
                float xn   = aX[mt][ct][r]      + bi[1024 + cglob];
                float hn   = aH[mt][ct][r]      + bhn[cglob];
                float rg = 1.f / (1.f + __expf(-rpre));
                float zg = 1.f / (1.f + __expf(-zpre));
                float targ = xn + rg * hn;
                float t2 = __expf(-2.f * fabsf(targ));
                float ng = copysignf((1.f - t2) / (1.f + t2), targ);
                float hp = 0.f;
                if (pi >= 0)
                    hp = YF32 ? ((const float*)Yv)[(size_t)pi * DDD + cglob]
                              : bf2f(((const u16*)Yv)[(size_t)pi * DDD + cglob]);
                else if (pi <= -2)
                    hp = hidden[(size_t)(-pi - 2) * DDD + cglob];
                float hnew = (1.f - zg) * ng + zg * hp;
                if (YF32) ((float*)Yv)[(size_t)p * DDD + cglob] = hnew;
                else      ((u16*)Yv)[(size_t)p * DDD + cglob] = f2bf(hnew);
            }
        }
    }
    __syncthreads();   // protect posL/As for next job
}

// ---------------- XCD-sharded GRU: per-XCD rounds, zero-fence barrier ----------------
template<bool YF32>
__global__ __launch_bounds__(256, 2) void gru_depth_k(
    const u16* __restrict__ E, const float* __restrict__ hidden,
    const u16* __restrict__ Wstk, const float* __restrict__ bi,
    const float* __restrict__ bhn,
    const int* __restrict__ list, const int* __restrict__ offs,
    const int* __restrict__ counts, const int* __restrict__ maxk,
    const int* __restrict__ pidxA,
    void* __restrict__ Yv, float* __restrict__ hid_out,
    int* __restrict__ xcdCnt)
{
    __shared__ u16 As[64 * 256];         // 32 KB
    __shared__ int posL[64], pidxL[64];
    __shared__ int sAnyH;
    const int tid = threadIdx.x;
    const int nblk = gridDim.x;
    const int e   = blockIdx.x & 7;      // XCD id (round-robin dispatch)
    const int xb  = blockIdx.x >> 3;     // block index within XCD
    const int nxb = nblk >> 3;           // blocks per XCD

    const int MKe = maxk[e];
    const int* cnt_e = counts + e * 512;
    const int* off_e = offs + e * 512;
    const int lb = e * 8192;             // this shard's list region
    int* cnt = xcdCnt + e * 32;          // this shard's barrier counter
    int round = 0;

    for (int k = 0; k <= MKe; k++) {
        const int nd = cnt_e[k];
        const int off = lb + off_e[k];
        const int njobs = ((nd + 63) >> 6) << 2;
        for (int lj = xb; lj < njobs; lj += nxb) {
            gru_job<YF32>(E, hidden, Wstk, bi, bhn, list, pidxA, Yv,
                          off, nd, lj >> 2, lj & 3, As, posL, pidxL, &sAnyH);
        }
        // zero-fence per-XCD barrier: monotonic relaxed RMW + relaxed spin.
        // __syncthreads drained this block's Y stores into the shared XCD L2;
        // co-XCD readers hit those dirty lines directly (no wb/inv needed).
        ++round;
        __syncthreads();
        if (tid == 0) {
            __hip_atomic_fetch_add(cnt, 1, __ATOMIC_RELAXED, __HIP_MEMORY_SCOPE_AGENT);
            const int target = round * nxb;
            while (AL_RLX(cnt) < target) __builtin_amdgcn_s_sleep(1);
        }
        __syncthreads();
    }

    // final hidden for this shard's columns: b in [32e, 32e+32)
    for (int i = xb * 256 + tid; i < 32 * DDD; i += nxb * 256) {
        int b = 32 * e + (i >> 9), c = i & 511;
        size_t yi = (size_t)(65280 + b) * DDD + c;
        hid_out[(size_t)b * DDD + c] =
            YF32 ? ((const float*)Yv)[yi] : bf2f(((const u16*)Yv)[yi]);
    }
}

extern "C" void kernel_launch(void* const* d_in, const int* in_sizes, int n_in,
                              void* d_out, int out_size, void* d_ws, size_t ws_size,
                              hipStream_t stream)
{
    const float* hidden = (const float*)d_in[0];
    const float* obs    = (const float*)d_in[1];
    const int*   dones  = (const int*)d_in[2];
    const int*   avail  = (const int*)d_in[3];
    const float* Wm     = (const float*)d_in[4];
    const float* bm     = (const float*)d_in[5];
    const float* lns    = (const float*)d_in[6];
    const float* lnb    = (const float*)d_in[7];
    const float* Wi     = (const float*)d_in[8];
    const float* bi     = (const float*)d_in[9];
    const float* Wh     = (const float*)d_in[10];
    const float* bhn    = (const float*)d_in[11];
    const float* Wo     = (const float*)d_in[12];
    const float* bo     = (const float*)d_in[13];
    const float* ln2s   = (const float*)d_in[14];
    const float* ln2b   = (const float*)d_in[15];
    const float* Wa     = (const float*)d_in[16];
    const float* ba     = (const float*)d_in[17];
    float* out = (float*)d_out;

    // workspace layout
    char* w = (char*)d_ws;
    u16* Wstk = (u16*)w;  w += (size_t)1536 * 1024 * 2;      // 3 MB
    u16* WmT  = (u16*)w;  w += (size_t)3 * DDD * DDD * 2;
    u16* WoT  = (u16*)w;  w += (size_t)DDD * DDD * 2;
    int* meta = (int*)w;  w += 65536;
    int* counts = meta;              // 8*512
    int* offs   = meta + 4096;       // 8*512
    int* cursor = meta + 8192;       // 8*512
    int* maxk   = meta + 12288;      // 8
    int* xcdCnt = meta + 12544;      // 8 x stride-32
    int* keyA   = (int*)w;  w += (size_t)MMM * 4;
    int* pidxA  = (int*)w;  w += (size_t)MMM * 4;
    int* list   = (int*)w;  w += (size_t)MMM * 4;
    u16* P = (u16*)w;       w += (size_t)MMM * DDD * 2;      // 64 MB
    void* Yv = (void*)w;
    const size_t base = (size_t)(w - (char*)d_ws);
    const bool yf32 = (ws_size >= base + (size_t)MMM * DDD * 4);

    // prep: weight transposes + meta zero
    dim3 tgrid(16, 16);
    for (int l = 0; l < 3; l++)
        transpose_cvt_k<<<tgrid, 256, 0, stream>>>(Wm + (size_t)l * DDD * DDD, WmT + (size_t)l * DDD * DDD, DDD);
    transpose_cvt_k<<<tgrid, 256, 0, stream>>>(Wo, WoT, DDD);
    for (int g = 0; g < 3; g++) {
        transpose_cvt_k<<<tgrid, 256, 0, stream>>>(Wi + (size_t)g * DDD * DDD, Wstk + (size_t)g * 512 * 1024, 1024);
        transpose_cvt_k<<<tgrid, 256, 0, stream>>>(Wh + (size_t)g * DDD * DDD, Wstk + (size_t)g * 512 * 1024 + 512, 1024);
    }
    hipMemsetAsync(meta, 0, 65536, stream);

    // per-XCD key lists (done-first within each shard)
    depth_build_k<<<1, 256, 0, stream>>>(dones, keyA, pidxA, counts, maxk);
    scan_k<<<1, 64, 0, stream>>>(counts, offs);
    scatter_k<<<MMM / 256, 256, 0, stream>>>(keyA, offs, cursor, list);

    // encoder: obs -> P -> Y -> P
    u16* Yq = (u16*)Yv;
    gemm_bf16_k<true><<<dim3(MMM / 128, 4), 256, 0, stream>>>(obs, WmT, bm, P, DDD);
    ln_relu_k<<<dim3(MMM / 4), 256, 0, stream>>>(P, lns, lnb);
    gemm_bf16_k<false><<<dim3(MMM / 128, 4), 256, 0, stream>>>(P, WmT + (size_t)DDD * DDD, bm + DDD, Yq, DDD);
    ln_relu_k<<<dim3(MMM / 4), 256, 0, stream>>>(Yq, lns + DDD, lnb + DDD);
    gemm_bf16_k<false><<<dim3(MMM / 128, 4), 256, 0, stream>>>(Yq, WmT + (size_t)2 * DDD * DDD, bm + 2 * DDD, P, DDD);
    ln_relu_k<<<dim3(MMM / 4), 256, 0, stream>>>(P, lns + 2 * DDD, lnb + 2 * DDD);

    // persistent-block XCD-sharded GRU; grid sized to guaranteed co-residency
    {
        const void* fptr = yf32 ? (const void*)gru_depth_k<true>
                                : (const void*)gru_depth_k<false>;
        int occ = 0;
        hipError_t err = hipOccupancyMaxActiveBlocksPerMultiprocessor(&occ, fptr, 256, 0);
        if (err != hipSuccess || occ < 1) occ = 2;
        if (occ > 4) occ = 4;
        dim3 grid(occ * 256);
        if (yf32)
            gru_depth_k<true><<<grid, 256, 0, stream>>>(
                P, hidden, Wstk, bi, bhn, list, offs, counts, maxk, pidxA,
                Yv, out, xcdCnt);
        else
            gru_depth_k<false><<<grid, 256, 0, stream>>>(
                P, hidden, Wstk, bi, bhn, list, offs, counts, maxk, pidxA,
                Yv, out, xcdCnt);
    }

    // head: Y -> P, LN, logits
    if (yf32)
        gemm_bf16_k<true><<<dim3(MMM / 128, 4), 256, 0, stream>>>(Yv, WoT, bo, P, DDD);
    else
        gemm_bf16_k<false><<<dim3(MMM / 128, 4), 256, 0, stream>>>(Yv, WoT, bo, P, DDD);
    ln_relu_k<<<dim3(MMM / 4), 256, 0, stream>>>(P, ln2s, ln2b);
    logits_k<<<dim3(MMM / 8), 256, 0, stream>>>(P, Wa, ba, avail, out + BBB * DDD);
}